// Round 1
// baseline (218.104 us; speedup 1.0000x reference)
//
#include <hip/hip_runtime.h>
#include <hip/hip_bf16.h>

// Problem constants (from reference)
#define T_ROWS   8192
#define K_DIM    4096
#define N_INT    63
#define N_LEAF   64
#define NCLS     10

typedef __bf16 bf16x8 __attribute__((ext_vector_type(8)));
typedef __bf16 bf16x4 __attribute__((ext_vector_type(4)));
typedef float  f32x4  __attribute__((ext_vector_type(4)));

// ---------------------------------------------------------------------------
// Prep: W (63x4096 fp32) -> Wb (64x4096 bf16, row 63 zeroed); leaf_r[64]
// ---------------------------------------------------------------------------
__global__ __launch_bounds__(256) void sdt_prep(
    const float* __restrict__ W,
    const float* __restrict__ leaf_dist,
    const float* __restrict__ class_reward,
    __bf16* __restrict__ Wb,
    float* __restrict__ leaf_r)
{
    int gid  = blockIdx.x * 256 + threadIdx.x;   // 65536 threads total
    int base = gid * 4;                          // element idx in 64x4096
    int n    = base >> 12;                       // row (4096 per row)
    bf16x4 v;
    if (n < N_INT) {
        const float4 w = *reinterpret_cast<const float4*>(W + base);
        v[0] = (__bf16)w.x; v[1] = (__bf16)w.y; v[2] = (__bf16)w.z; v[3] = (__bf16)w.w;
    } else {
        v[0] = (__bf16)0.0f; v[1] = (__bf16)0.0f; v[2] = (__bf16)0.0f; v[3] = (__bf16)0.0f;
    }
    *reinterpret_cast<bf16x4*>(Wb + base) = v;

    if (blockIdx.x == 0 && threadIdx.x < N_LEAF) {
        int i = threadIdx.x;
        float m = -1e30f;
        #pragma unroll
        for (int j = 0; j < NCLS; ++j) m = fmaxf(m, leaf_dist[i * NCLS + j]);
        float s = 0.0f, d = 0.0f;
        #pragma unroll
        for (int j = 0; j < NCLS; ++j) {
            float e = expf(leaf_dist[i * NCLS + j] - m);
            s += e;
            d += e * class_reward[j];
        }
        leaf_r[i] = d / s;
    }
}

// ---------------------------------------------------------------------------
// Main: fused GEMM (bf16 MFMA) + sigmoid + tree propagation + reduce
// 512 blocks x 512 threads (8 waves). BM=16 rows/block, wave-split K (512 ea).
// ---------------------------------------------------------------------------
__global__ __launch_bounds__(512, 4) void sdt_main(
    const float* __restrict__ X,       // 8192 x 4096 fp32
    const __bf16* __restrict__ Wb,     // 64 x 4096 bf16
    const float* __restrict__ b,       // 63
    const float* __restrict__ beta,    // 63
    const float* __restrict__ leaf_r,  // 64
    float* __restrict__ out)           // scalar
{
    // Padded stride 65 breaks the 4-quad bank alias on the accumulator dump.
    __shared__ float red[8 * 16 * 65];   // per-wave C copies
    __shared__ float Pbuf[16 * 64];      // sigmoid'd node probs per row
    __shared__ float sred[8];

    const int tid  = threadIdx.x;
    const int wid  = tid >> 6;
    const int lane = tid & 63;
    const int m16  = lane & 15;          // A row within tile / C col
    const int q    = lane >> 4;          // quad

    const int row0 = blockIdx.x * 16;
    const float* Arow = X + (size_t)(row0 + m16) * K_DIM;

    f32x4 acc[4];
    #pragma unroll
    for (int g = 0; g < 4; ++g) acc[g] = (f32x4){0.0f, 0.0f, 0.0f, 0.0f};

    const int kbase = wid * (K_DIM / 8); // 512 K per wave

    #pragma unroll 2
    for (int it = 0; it < 16; ++it) {
        const int k0 = kbase + it * 32 + q * 8;
        // A fragment: 8 contiguous fp32 -> bf16 (layout: A[m=lane&15][k=q*8+j])
        const float4 a0 = *reinterpret_cast<const float4*>(Arow + k0);
        const float4 a1 = *reinterpret_cast<const float4*>(Arow + k0 + 4);
        bf16x8 af;
        af[0] = (__bf16)a0.x; af[1] = (__bf16)a0.y;
        af[2] = (__bf16)a0.z; af[3] = (__bf16)a0.w;
        af[4] = (__bf16)a1.x; af[5] = (__bf16)a1.y;
        af[6] = (__bf16)a1.z; af[7] = (__bf16)a1.w;
        #pragma unroll
        for (int g = 0; g < 4; ++g) {
            // B fragment: B[k=q*8+j][n=g*16+(lane&15)] = Wb[n][k] (L2-hot)
            const bf16x8 bf = *reinterpret_cast<const bf16x8*>(
                Wb + (size_t)(g * 16 + m16) * K_DIM + k0);
            acc[g] = __builtin_amdgcn_mfma_f32_16x16x32_bf16(af, bf, acc[g], 0, 0, 0);
        }
    }

    // Dump per-wave partial C: C[row=q*4+r][col=g*16+m16]
    #pragma unroll
    for (int g = 0; g < 4; ++g)
        #pragma unroll
        for (int r = 0; r < 4; ++r)
            red[(wid * 16 + q * 4 + r) * 65 + g * 16 + m16] = acc[g][r];
    __syncthreads();

    // Reduce 8 wave copies -> logits -> P = sigmoid(beta*(l+b))
    for (int e = tid; e < 16 * 64; e += 512) {
        const int r = e >> 6, c = e & 63;
        float s = 0.0f;
        #pragma unroll
        for (int w = 0; w < 8; ++w) s += red[(w * 16 + r) * 65 + c];
        float P = 0.0f;
        if (c < N_INT) {
            const float z = beta[c] * (s + b[c]);
            P = 1.0f / (1.0f + __expf(-z));
        }
        Pbuf[r * 64 + c] = P;
    }
    __syncthreads();

    // Tree: thread -> (row = tid>>5, 2 leaves). leaf path product * leaf_r.
    const int row  = tid >> 5;
    const int pair = tid & 31;
    float score = 0.0f;
    #pragma unroll
    for (int u = 0; u < 2; ++u) {
        const int leaf = pair * 2 + u;
        float prod = 1.0f;
        #pragma unroll
        for (int k = 0; k < 6; ++k) {
            const int node = ((1 << k) - 1) + (leaf >> (6 - k));
            const float p  = Pbuf[row * 64 + node];
            const int bit  = (leaf >> (5 - k)) & 1;
            prod *= bit ? (1.0f - p) : p;
        }
        score += prod * leaf_r[leaf];
    }

    // Block reduction -> one atomicAdd per block
    #pragma unroll
    for (int off = 32; off > 0; off >>= 1)
        score += __shfl_down(score, off, 64);
    if (lane == 0) sred[wid] = score;
    __syncthreads();
    if (tid == 0) {
        float s = 0.0f;
        #pragma unroll
        for (int w = 0; w < 8; ++w) s += sred[w];
        atomicAdd(out, s);
    }
}

// ---------------------------------------------------------------------------
extern "C" void kernel_launch(void* const* d_in, const int* in_sizes, int n_in,
                              void* d_out, int out_size, void* d_ws, size_t ws_size,
                              hipStream_t stream)
{
    const float* X           = (const float*)d_in[0];
    const float* W           = (const float*)d_in[1];
    const float* b           = (const float*)d_in[2];
    const float* beta        = (const float*)d_in[3];
    const float* leaf_dist   = (const float*)d_in[4];
    const float* class_rew   = (const float*)d_in[5];
    float* out               = (float*)d_out;

    __bf16* Wb    = (__bf16*)d_ws;                                  // 64*4096*2 B
    float*  leafr = (float*)((char*)d_ws + (size_t)N_LEAF * K_DIM * 2);

    hipMemsetAsync(d_out, 0, sizeof(float), stream);                // ws/out are poisoned each replay
    sdt_prep<<<256, 256, 0, stream>>>(W, leaf_dist, class_rew, Wb, leafr);
    sdt_main<<<T_ROWS / 16, 512, 0, stream>>>(X, Wb, b, beta, leafr, out);
}